// Round 1
// 1335.130 us; speedup vs baseline: 1.3461x; 1.3461x over previous
//
#include <hip/hip_runtime.h>

// ---------------------------------------------------------------------------
// PoseVQVAE fused forward. DUAL-MODE storage dtype (f32 vs bf16) sniffed
// on-device. Math core: bf16 MFMA, encoder 3-plane splits (split on READ
// from f32 LDS activations), decoder 1-plane.
// This round: fused enc+dec single kernel, 256 threads (4 waves, col-split
// wave pairs), f32 single-plane activation LDS -> ~40.6KB LDS -> 4 blk/CU
// x 4 waves = 16 waves/CU (was 6). Targets the latency-bound 7.8% MfmaUtil.
// ---------------------------------------------------------------------------

using short8 = __attribute__((ext_vector_type(8))) short;
using f32x4  = __attribute__((ext_vector_type(4))) float;

#define USHORT unsigned short
#define UINT   unsigned int

// plane sizes in ushorts
#define PS_W1  139264   // 544*256
#define PS_W2  65536    // 256*256
#define PS_MU  16384    // 256*64
#define PS_WE  65536    // 64*1024

// LDS geometry
#define STRF 260        // f32 activation stride (260 mod 32 == 4 -> even bank spread)
#define STRA 360        // dec sA stride (ushort)
#define STRB 264        // dec sB stride (ushort)

// ---- ws layout (bytes), 64B-aligned ----
static const size_t OFF_IDX    = 0;         // (unused now, kept for layout stability)
static const size_t OFF_COUNTS = 262144;    // 1024*4
static const size_t OFF_LOSS   = 266240;    // 4 (+pad)
static const size_t OFF_ENORM  = 266304;    // 1024*4
static const size_t OFF_W1     = 270400;    // 3 planes * 139264 * 2 = 835584
static const size_t OFF_W2     = 1105984;   // 3*65536*2 = 393216
static const size_t OFF_W3     = 1499200;   // 393216
static const size_t OFF_WMU    = 1892416;   // 3*16384*2 = 98304
static const size_t OFF_WE     = 1990720;   // 3*65536*2 = 393216
static const size_t OFF_W4     = 2383936;   // 352*256*2 = 180224
static const size_t OFF_W5     = 2564160;   // 131072
static const size_t OFF_W6     = 2695232;   // 131072
static const size_t OFF_WO     = 2826304;   // 256*272*2 = 139264 -> end ~2.97MB

__device__ __forceinline__ float b2f(USHORT u){
  return __uint_as_float(((UINT)u) << 16);
}
__device__ __forceinline__ USHORT f2b(float f){            // RNE f32->bf16
  UINT u = __float_as_uint(f);
  u += 0x7fffu + ((u >> 16) & 1u);
  return (USHORT)(u >> 16);
}
__device__ __forceinline__ float loadF(const void* p, long i, int f32m){
  if (f32m) return ((const float*)p)[i];
  return b2f(((const USHORT*)p)[i]);
}
__device__ __forceinline__ void split3(float h, USHORT& a, USHORT& b, USHORT& c){
  a = f2b(h); float r = h - b2f(a);
  b = f2b(r); r -= b2f(b);
  c = f2b(r);
}
__device__ __forceinline__ f32x4 mfma16(short8 a, short8 b, f32x4 c){
  return __builtin_amdgcn_mfma_f32_16x16x32_bf16(a, b, c, 0, 0, 0);
}
// build 3 A-planes from 8 consecutive f32 in LDS
__device__ __forceinline__ void splitA(const float* p, short8& A0, short8& A1, short8& A2){
  #pragma unroll
  for (int j = 0; j < 8; ++j){
    USHORT t0, t1, t2; split3(p[j], t0, t1, t2);
    A0[j] = (short)t0; A1[j] = (short)t1; A2[j] = (short)t2;
  }
}
// dtype sniff (wave-uniform): bf16 storage -> low u16 exponent in [117,130]
__device__ __forceinline__ int detect_f32(const void* x){
  UINT u = ((const UINT*)x)[threadIdx.x & 63];
  int e = (int)((u >> 7) & 0xFFu);
  unsigned long long m = __ballot(e >= 117 && e <= 130);
  return __popcll(m) < 32;
}

// ---------------------------------------------------------------------------
// prep: repack weights into [K/8][N][8] bf16 planes; enorm; zero accums.
// ---------------------------------------------------------------------------
__device__ __forceinline__ void fillW(USHORT* dst, const void* src,
                                      int Kpad, int N, int Ksrc, int Nsrc,
                                      int srcStride, bool kmajor, int t,
                                      int f32m, int planes)
{
  int total = Kpad * N;
  if (t >= total) return;
  int j = t & 7, rest = t >> 3;
  int n = rest % N, kg = rest / N;
  int k = kg*8 + j;
  float v = 0.f;
  if (k < Ksrc && n < Nsrc)
    v = loadF(src, kmajor ? (long)k*srcStride + n : (long)n*srcStride + k, f32m);
  if (planes == 1){ dst[t] = f2b(v); return; }
  USHORT t0, t1, t2; split3(v, t0, t1, t2);
  dst[t] = t0; dst[total + t] = t1; dst[2*total + t] = t2;
}

__global__ void vq_prep_kernel(
    const void* xx,
    const void* fc1w, const void* fc2w, const void* fc3w,
    const void* muw,  const void* fc4w, const void* fc5w,
    const void* fc6w, const void* outw, const void* embed,
    USHORT* W1p, USHORT* W2p, USHORT* W3p, USHORT* Wmup, USHORT* Wep,
    USHORT* W4p, USHORT* W5p, USHORT* W6p, USHORT* Wop,
    float* enorm, UINT* counts, float* loss_sum)
{
  int f32m = detect_f32(xx);
  int t = blockIdx.x * 256 + threadIdx.x;
  switch (blockIdx.y){
    case 0: fillW(W1p,  fc1w, 544, 256, 534, 256, 534, false, t, f32m, 3); break;
    case 1: fillW(W2p,  fc2w, 256, 256, 256, 256, 256, false, t, f32m, 3); break;
    case 2: fillW(W3p,  fc3w, 256, 256, 256, 256, 256, false, t, f32m, 3); break;
    case 3: fillW(Wmup, muw,  256,  64, 256,  64, 256, false, t, f32m, 3); break;
    case 4: fillW(Wep,  embed, 64, 1024, 64, 1024, 1024, true, t, f32m, 3); break;
    case 5: fillW(W4p,  fc4w, 352, 256, 331, 256, 331, false, t, f32m, 1); break;
    case 6: fillW(W5p,  fc5w, 256, 256, 256, 256, 256, false, t, f32m, 1); break;
    case 7: fillW(W6p,  fc6w, 256, 256, 256, 256, 256, false, t, f32m, 1); break;
    case 8: fillW(Wop,  outw, 256, 272, 256, 267, 256, false, t, f32m, 1); break;
    case 9:
      if (t < 1024){
        double s = 0.0;
        for (int l = 0; l < 64; ++l){
          double e = (double)loadF(embed, (long)l*1024 + t, f32m); s += e*e;
        }
        enorm[t] = (float)s;
      }
      break;
    case 10:
      if (t < 1024) counts[t] = 0u;
      if (t == 1024) *loss_sum = 0.f;
      break;
  }
}

// ---------------------------------------------------------------------------
// fused main: 32 rows/block, 256 threads (4 waves).
//   wave w: rowHalf = w&1 (rows rowHalf*16..+15), colHalf = w>>1 (N split).
// encoder: f32 activations in LDS [32][STRF], split3 on A-read (exact same
// numerics as plane-split-on-write). decoder: bf16 1-plane, aliased LDS.
// ---------------------------------------------------------------------------
__global__ __launch_bounds__(256, 4) void vq_main_kernel(
    const void* __restrict__ x,  const void* __restrict__ cc,
    const void* __restrict__ b1, const void* __restrict__ b2,
    const void* __restrict__ b3, const void* __restrict__ bmu,
    const void* __restrict__ b4, const void* __restrict__ b5,
    const void* __restrict__ b6, const void* __restrict__ bo,
    const void* __restrict__ embed,
    const USHORT* __restrict__ W1p, const USHORT* __restrict__ W2p,
    const USHORT* __restrict__ W3p, const USHORT* __restrict__ Wmup,
    const USHORT* __restrict__ Wep, const float* __restrict__ enorm,
    const USHORT* __restrict__ W4p, const USHORT* __restrict__ W5p,
    const USHORT* __restrict__ W6p, const USHORT* __restrict__ Wop,
    UINT* __restrict__ counts, float* __restrict__ loss_sum,
    void* __restrict__ out)
{
  // union buffer: enc f32 acts [32][260] (33280B) ALIASED with
  // dec sA [32][360] (23040B) + sB [32][264] (16896B) = 39936B
  __shared__ __align__(16) char U[39936];
  __shared__ float rMin[2][32];
  __shared__ int   rCode[2][32];
  __shared__ int   codes[32];
  float*  sF = (float*)U;
  USHORT* sA = (USHORT*)U;
  USHORT* sB = (USHORT*)(U + 23040);

  const int f32m = detect_f32(x);
  const int tid  = threadIdx.x;
  const int w    = tid >> 6;
  const int lane = tid & 63;
  const int quad = lane >> 4;
  const int l16  = lane & 15;
  const int rowHalf = w & 1;
  const int colHalf = w >> 1;
  const int row  = rowHalf*16 + l16;          // A-fragment row (wave-private)
  const int cbase = colHalf*128;              // N-split base for 256-wide layers
  const long gbase = (long)blockIdx.x * 32;
  const long gr    = gbase + row;

  f32x4 acc[8];
  #pragma unroll
  for (int i = 0; i < 8; ++i){ acc[i][0]=0.f; acc[i][1]=0.f; acc[i][2]=0.f; acc[i][3]=0.f; }

  // ================= encoder =================
  // ---- fc1: K=544 (17 chunks); A from global (wave pairs duplicate, L1-hit)
  for (int kc = 0; kc < 17; ++kc){
    short8 A0, A1, A2;
    #pragma unroll
    for (int j = 0; j < 8; ++j){
      int col = kc*32 + quad*8 + j;
      float v = 0.f;
      if (col < 267)      v = loadF(x,  gr*267 + col, f32m);
      else if (col < 534) v = loadF(cc, gr*267 + (col - 267), f32m);
      USHORT t0, t1, t2; split3(v, t0, t1, t2);
      A0[j] = (short)t0; A1[j] = (short)t1; A2[j] = (short)t2;
    }
    const USHORT* w0 = W1p + ((kc*4 + quad)*256 + cbase + l16)*8;
    short8 Bf[8];
    #pragma unroll
    for (int cb = 0; cb < 8; ++cb) Bf[cb] = *(const short8*)(w0 + cb*128);
    if (!f32m){
      #pragma unroll
      for (int cb = 0; cb < 8; ++cb) acc[cb] = mfma16(A0, Bf[cb], acc[cb]);
    } else {
      #pragma unroll
      for (int cb = 0; cb < 8; ++cb) acc[cb] = mfma16(A0, Bf[cb], acc[cb]);
      #pragma unroll
      for (int cb = 0; cb < 8; ++cb) acc[cb] = mfma16(A1, Bf[cb], acc[cb]);
      #pragma unroll
      for (int cb = 0; cb < 8; ++cb) acc[cb] = mfma16(A2, Bf[cb], acc[cb]);
      const USHORT* w1 = w0 + PS_W1;
      #pragma unroll
      for (int cb = 0; cb < 8; ++cb) Bf[cb] = *(const short8*)(w1 + cb*128);
      #pragma unroll
      for (int cb = 0; cb < 8; ++cb) acc[cb] = mfma16(A0, Bf[cb], acc[cb]);
      #pragma unroll
      for (int cb = 0; cb < 8; ++cb) acc[cb] = mfma16(A1, Bf[cb], acc[cb]);
      const USHORT* w2 = w0 + 2*PS_W1;
      #pragma unroll
      for (int cb = 0; cb < 8; ++cb) Bf[cb] = *(const short8*)(w2 + cb*128);
      #pragma unroll
      for (int cb = 0; cb < 8; ++cb) acc[cb] = mfma16(A0, Bf[cb], acc[cb]);
    }
  }
  #pragma unroll
  for (int cb = 0; cb < 8; ++cb){
    int col = cbase + cb*16 + l16;
    float bias = loadF(b1, col, f32m);
    #pragma unroll
    for (int r = 0; r < 4; ++r){
      int orow = rowHalf*16 + quad*4 + r;
      sF[orow*STRF + col] = fmaxf(acc[cb][r] + bias, 0.f);
    }
  }
  __syncthreads();

  // ---- fc2, fc3: in-place f32 LDS, split3-on-read, K=256
  for (int layer = 0; layer < 2; ++layer){
    const USHORT* Wp = layer ? W3p : W2p;
    const void*   bb = layer ? (const void*)b3 : (const void*)b2;
    #pragma unroll
    for (int i = 0; i < 8; ++i){ acc[i][0]=0.f; acc[i][1]=0.f; acc[i][2]=0.f; acc[i][3]=0.f; }
    for (int kc = 0; kc < 8; ++kc){
      short8 A0, A1, A2;
      splitA(&sF[row*STRF + kc*32 + quad*8], A0, A1, A2);
      const USHORT* w0 = Wp + ((kc*4 + quad)*256 + cbase + l16)*8;
      short8 Bf[8];
      #pragma unroll
      for (int cb = 0; cb < 8; ++cb) Bf[cb] = *(const short8*)(w0 + cb*128);
      #pragma unroll
      for (int cb = 0; cb < 8; ++cb) acc[cb] = mfma16(A0, Bf[cb], acc[cb]);
      #pragma unroll
      for (int cb = 0; cb < 8; ++cb) acc[cb] = mfma16(A1, Bf[cb], acc[cb]);
      #pragma unroll
      for (int cb = 0; cb < 8; ++cb) acc[cb] = mfma16(A2, Bf[cb], acc[cb]);
      if (f32m){
        const USHORT* w1 = w0 + PS_W2;
        #pragma unroll
        for (int cb = 0; cb < 8; ++cb) Bf[cb] = *(const short8*)(w1 + cb*128);
        #pragma unroll
        for (int cb = 0; cb < 8; ++cb) acc[cb] = mfma16(A0, Bf[cb], acc[cb]);
        #pragma unroll
        for (int cb = 0; cb < 8; ++cb) acc[cb] = mfma16(A1, Bf[cb], acc[cb]);
        const USHORT* w2 = w0 + 2*PS_W2;
        #pragma unroll
        for (int cb = 0; cb < 8; ++cb) Bf[cb] = *(const short8*)(w2 + cb*128);
        #pragma unroll
        for (int cb = 0; cb < 8; ++cb) acc[cb] = mfma16(A0, Bf[cb], acc[cb]);
      }
    }
    __syncthreads();
    #pragma unroll
    for (int cb = 0; cb < 8; ++cb){
      int col = cbase + cb*16 + l16;
      float bias = loadF(bb, col, f32m);
      #pragma unroll
      for (int r = 0; r < 4; ++r){
        int orow = rowHalf*16 + quad*4 + r;
        sF[orow*STRF + col] = fmaxf(acc[cb][r] + bias, 0.f);
      }
    }
    __syncthreads();
  }

  // ---- mu: N=64 (2 cb per wave), no relu; result into sF cols 0..63
  {
    f32x4 accm[2];
    #pragma unroll
    for (int i = 0; i < 2; ++i){ accm[i][0]=0.f; accm[i][1]=0.f; accm[i][2]=0.f; accm[i][3]=0.f; }
    for (int kc = 0; kc < 8; ++kc){
      short8 A0, A1, A2;
      splitA(&sF[row*STRF + kc*32 + quad*8], A0, A1, A2);
      const USHORT* w0 = Wmup + ((kc*4 + quad)*64 + colHalf*32 + l16)*8;
      short8 Bm[2];
      #pragma unroll
      for (int cb = 0; cb < 2; ++cb) Bm[cb] = *(const short8*)(w0 + cb*128);
      #pragma unroll
      for (int cb = 0; cb < 2; ++cb) accm[cb] = mfma16(A0, Bm[cb], accm[cb]);
      #pragma unroll
      for (int cb = 0; cb < 2; ++cb) accm[cb] = mfma16(A1, Bm[cb], accm[cb]);
      #pragma unroll
      for (int cb = 0; cb < 2; ++cb) accm[cb] = mfma16(A2, Bm[cb], accm[cb]);
      if (f32m){
        const USHORT* w1 = w0 + PS_MU;
        #pragma unroll
        for (int cb = 0; cb < 2; ++cb) Bm[cb] = *(const short8*)(w1 + cb*128);
        #pragma unroll
        for (int cb = 0; cb < 2; ++cb) accm[cb] = mfma16(A0, Bm[cb], accm[cb]);
        #pragma unroll
        for (int cb = 0; cb < 2; ++cb) accm[cb] = mfma16(A1, Bm[cb], accm[cb]);
        const USHORT* w2 = w0 + 2*PS_MU;
        #pragma unroll
        for (int cb = 0; cb < 2; ++cb) Bm[cb] = *(const short8*)(w2 + cb*128);
        #pragma unroll
        for (int cb = 0; cb < 2; ++cb) accm[cb] = mfma16(A0, Bm[cb], accm[cb]);
      }
    }
    __syncthreads();
    #pragma unroll
    for (int cb = 0; cb < 2; ++cb){
      int col = colHalf*32 + cb*16 + l16;
      float bias = loadF(bmu, col, f32m);
      #pragma unroll
      for (int r = 0; r < 4; ++r){
        int orow = rowHalf*16 + quad*4 + r;
        sF[orow*STRF + col] = accm[cb][r] + bias;
      }
    }
    __syncthreads();
  }

  // ---- VQ: argmin over 1024 codes; wave pair splits codes 512/512
  {
    short8 MA0[2], MA1[2], MA2[2];
    #pragma unroll
    for (int kc = 0; kc < 2; ++kc)
      splitA(&sF[row*STRF + kc*32 + quad*8], MA0[kc], MA1[kc], MA2[kc]);
    float minv[4] = {3.4e38f, 3.4e38f, 3.4e38f, 3.4e38f};
    int   minc[4] = {0,0,0,0};
    for (int it = 0; it < 16; ++it){          // 32 codes/iter, 512 per wave
      f32x4 ad0, ad1;
      ad0[0]=0.f; ad0[1]=0.f; ad0[2]=0.f; ad0[3]=0.f;
      ad1[0]=0.f; ad1[1]=0.f; ad1[2]=0.f; ad1[3]=0.f;
      #pragma unroll
      for (int kc = 0; kc < 2; ++kc){
        const USHORT* w0 = Wep + ((kc*4 + quad)*1024 + colHalf*512 + it*32 + l16)*8;
        short8 B00 = *(const short8*)(w0);
        short8 B01 = *(const short8*)(w0 + 128);
        ad0 = mfma16(MA0[kc], B00, ad0);  ad1 = mfma16(MA0[kc], B01, ad1);
        ad0 = mfma16(MA1[kc], B00, ad0);  ad1 = mfma16(MA1[kc], B01, ad1);
        ad0 = mfma16(MA2[kc], B00, ad0);  ad1 = mfma16(MA2[kc], B01, ad1);
        if (f32m){
          const USHORT* w1 = w0 + PS_WE;
          short8 B10 = *(const short8*)(w1);
          short8 B11 = *(const short8*)(w1 + 128);
          ad0 = mfma16(MA0[kc], B10, ad0);  ad1 = mfma16(MA0[kc], B11, ad1);
          ad0 = mfma16(MA1[kc], B10, ad0);  ad1 = mfma16(MA1[kc], B11, ad1);
          const USHORT* w2 = w0 + 2*PS_WE;
          short8 B20 = *(const short8*)(w2);
          short8 B21 = *(const short8*)(w2 + 128);
          ad0 = mfma16(MA0[kc], B20, ad0);  ad1 = mfma16(MA0[kc], B21, ad1);
        }
      }
      int code0 = colHalf*512 + it*32 + l16, code1 = code0 + 16;
      float en0 = enorm[code0], en1 = enorm[code1];
      #pragma unroll
      for (int r = 0; r < 4; ++r){
        float d0 = en0 - 2.f*ad0[r];
        if (d0 < minv[r] || (d0 == minv[r] && code0 < minc[r])){ minv[r] = d0; minc[r] = code0; }
        float d1 = en1 - 2.f*ad1[r];
        if (d1 < minv[r] || (d1 == minv[r] && code1 < minc[r])){ minv[r] = d1; minc[r] = code1; }
      }
    }
    // reduce across 16 lanes of each quad (ties -> lowest index)
    #pragma unroll
    for (int off = 8; off >= 1; off >>= 1){
      #pragma unroll
      for (int r = 0; r < 4; ++r){
        float ov = __shfl_xor(minv[r], off, 64);
        int   oc = __shfl_xor(minc[r], off, 64);
        if (ov < minv[r] || (ov == minv[r] && oc < minc[r])){ minv[r] = ov; minc[r] = oc; }
      }
    }
    if (l16 == 0){
      #pragma unroll
      for (int r = 0; r < 4; ++r){
        int lr = rowHalf*16 + quad*4 + r;
        rMin[colHalf][lr]  = minv[r];
        rCode[colHalf][lr] = minc[r];
      }
    }
  }
  __syncthreads();

  // combine wave-pair halves, emit codes + histogram
  if (tid < 32){
    float v0 = rMin[0][tid], v1 = rMin[1][tid];
    int   c0 = rCode[0][tid], c1 = rCode[1][tid];
    int code = (v1 < v0 || (v1 == v0 && c1 < c0)) ? c1 : c0;
    codes[tid] = code;
    atomicAdd(&counts[code], 1u);
  }
  __syncthreads();

  // loss: each wave covers its 16 rows x 32 latent dims (colHalf splits j)
  {
    float lossp = 0.f;
    #pragma unroll
    for (int r = 0; r < 4; ++r){
      int orow = rowHalf*16 + quad*4 + r;
      int code = codes[orow];
      #pragma unroll
      for (int jj = 0; jj < 2; ++jj){
        int l = l16 + (colHalf*2 + jj)*16;
        float qv  = loadF(embed, (long)l*1024 + code, f32m);
        float muf = sF[orow*STRF + l];
        float d = qv - muf;
        lossp += d*d;
      }
    }
    #pragma unroll
    for (int off = 32; off >= 1; off >>= 1) lossp += __shfl_xor(lossp, off, 64);
    if (lane == 0) atomicAdd(loss_sum, lossp);
  }
  __syncthreads();   // all sF reads done before sA overwrite

  // ================= decoder (bf16 1-plane) =================
  // stage s2 = [q | c | 0pad] width 360 (331 used); each wave stages 8 rows
  for (int rr = w*8; rr < w*8 + 8; ++rr){
    int code = codes[rr];
    long grow = gbase + rr;
    for (int col = lane; col < 360; col += 64){
      float v = 0.f;
      if (col < 64)       v = loadF(embed, (long)col*1024 + code, f32m);
      else if (col < 331) v = loadF(cc, grow*267 + (col - 64), f32m);
      sA[rr*STRA + col] = f2b(v);
    }
  }
  __syncthreads();

  // ---- fc4: K=352 (11 chunks) : sA -> sB
  #pragma unroll
  for (int i = 0; i < 8; ++i){ acc[i][0]=0.f; acc[i][1]=0.f; acc[i][2]=0.f; acc[i][3]=0.f; }
  for (int kc = 0; kc < 11; ++kc){
    short8 A = *(const short8*)&sA[row*STRA + kc*32 + quad*8];
    const USHORT* wp = W4p + ((kc*4 + quad)*256 + cbase + l16)*8;
    #pragma unroll
    for (int cb = 0; cb < 8; ++cb){
      short8 Bf = *(const short8*)(wp + cb*128);
      acc[cb] = mfma16(A, Bf, acc[cb]);
    }
  }
  __syncthreads();
  #pragma unroll
  for (int cb = 0; cb < 8; ++cb){
    int col = cbase + cb*16 + l16;
    float bias = loadF(b4, col, f32m);
    #pragma unroll
    for (int r = 0; r < 4; ++r){
      int orow = rowHalf*16 + quad*4 + r;
      sB[orow*STRB + col] = f2b(fmaxf(acc[cb][r] + bias, 0.f));
    }
  }
  __syncthreads();

  // ---- fc5: sB -> sA
  #pragma unroll
  for (int i = 0; i < 8; ++i){ acc[i][0]=0.f; acc[i][1]=0.f; acc[i][2]=0.f; acc[i][3]=0.f; }
  for (int kc = 0; kc < 8; ++kc){
    short8 A = *(const short8*)&sB[row*STRB + kc*32 + quad*8];
    const USHORT* wp = W5p + ((kc*4 + quad)*256 + cbase + l16)*8;
    #pragma unroll
    for (int cb = 0; cb < 8; ++cb){
      short8 Bf = *(const short8*)(wp + cb*128);
      acc[cb] = mfma16(A, Bf, acc[cb]);
    }
  }
  __syncthreads();
  #pragma unroll
  for (int cb = 0; cb < 8; ++cb){
    int col = cbase + cb*16 + l16;
    float bias = loadF(b5, col, f32m);
    #pragma unroll
    for (int r = 0; r < 4; ++r){
      int orow = rowHalf*16 + quad*4 + r;
      sA[orow*STRA + col] = f2b(fmaxf(acc[cb][r] + bias, 0.f));
    }
  }
  __syncthreads();

  // ---- fc6: sA -> sB
  #pragma unroll
  for (int i = 0; i < 8; ++i){ acc[i][0]=0.f; acc[i][1]=0.f; acc[i][2]=0.f; acc[i][3]=0.f; }
  for (int kc = 0; kc < 8; ++kc){
    short8 A = *(const short8*)&sA[row*STRA + kc*32 + quad*8];
    const USHORT* wp = W6p + ((kc*4 + quad)*256 + cbase + l16)*8;
    #pragma unroll
    for (int cb = 0; cb < 8; ++cb){
      short8 Bf = *(const short8*)(wp + cb*128);
      acc[cb] = mfma16(A, Bf, acc[cb]);
    }
  }
  __syncthreads();
  #pragma unroll
  for (int cb = 0; cb < 8; ++cb){
    int col = cbase + cb*16 + l16;
    float bias = loadF(b6, col, f32m);
    #pragma unroll
    for (int r = 0; r < 4; ++r){
      int orow = rowHalf*16 + quad*4 + r;
      sB[orow*STRB + col] = f2b(fmaxf(acc[cb][r] + bias, 0.f));
    }
  }
  __syncthreads();

  // ---- out: N=272 (267 real), split 9 cbs (cols 0-143) / 8 cbs (144-271)
  {
    const int obase = colHalf*144;
    const int ncb = 9 - colHalf;
    f32x4 acco[9];
    #pragma unroll
    for (int i = 0; i < 9; ++i){ acco[i][0]=0.f; acco[i][1]=0.f; acco[i][2]=0.f; acco[i][3]=0.f; }
    for (int kc = 0; kc < 8; ++kc){
      short8 A = *(const short8*)&sB[row*STRB + kc*32 + quad*8];
      const USHORT* wp = Wop + ((kc*4 + quad)*272 + obase + l16)*8;
      #pragma unroll
      for (int cb = 0; cb < 9; ++cb){
        if (cb < ncb){
          short8 Bf = *(const short8*)(wp + cb*128);
          acco[cb] = mfma16(A, Bf, acco[cb]);
        }
      }
    }
    #pragma unroll
    for (int cb = 0; cb < 9; ++cb){
      if (cb < ncb){
        int col = obase + cb*16 + l16;
        if (col < 267){
          float bias = loadF(bo, col, f32m);
          #pragma unroll
          for (int r = 0; r < 4; ++r){
            int orow = rowHalf*16 + quad*4 + r;
            long oi = (gbase + orow)*267 + col;
            float val = acco[cb][r] + bias;
            if (f32m) ((float*)out)[oi] = val;
            else      ((USHORT*)out)[oi] = f2b(val);
          }
        }
      }
    }
  }
}

// ---------------------------------------------------------------------------
// finalize: loss mean + perplexity from histogram
// ---------------------------------------------------------------------------
__global__ void vq_fin_kernel(const void* __restrict__ x,
                              const UINT* __restrict__ counts,
                              const float* __restrict__ loss_sum,
                              void* __restrict__ out)
{
  __shared__ float red[4];
  int f32m = detect_f32(x);
  int tid = threadIdx.x;
  float Hl = 0.f;
  for (int k = tid; k < 1024; k += 256){
    float p = (float)counts[k] * (1.f/65536.f);
    Hl -= p * logf(p + 1e-10f);
  }
  #pragma unroll
  for (int off = 32; off >= 1; off >>= 1) Hl += __shfl_xor(Hl, off, 64);
  if ((tid & 63) == 0) red[tid >> 6] = Hl;
  __syncthreads();
  if (tid == 0){
    float H = red[0] + red[1] + red[2] + red[3];
    float loss = *loss_sum * (1.f/4194304.f);   // /(B*L)
    float ppx  = expf(H);
    size_t base = (size_t)65536*267;
    if (f32m){
      ((float*)out)[base]     = loss;
      ((float*)out)[base + 1] = ppx;
    } else {
      ((USHORT*)out)[base]     = f2b(loss);
      ((USHORT*)out)[base + 1] = f2b(ppx);
    }
  }
}

// ---------------------------------------------------------------------------
extern "C" void kernel_launch(void* const* d_in, const int* in_sizes, int n_in,
                              void* d_out, int out_size, void* d_ws, size_t ws_size,
                              hipStream_t stream)
{
  const void* x    = d_in[0];
  const void* c    = d_in[1];
  const void* fc1w = d_in[2];
  const void* fc1b = d_in[3];
  const void* fc2w = d_in[4];
  const void* fc2b = d_in[5];
  const void* fc3w = d_in[6];
  const void* fc3b = d_in[7];
  const void* muw  = d_in[8];
  const void* mub  = d_in[9];
  const void* fc4w = d_in[10];
  const void* fc4b = d_in[11];
  const void* fc5w = d_in[12];
  const void* fc5b = d_in[13];
  const void* fc6w = d_in[14];
  const void* fc6b = d_in[15];
  const void* outw = d_in[16];
  const void* outb = d_in[17];
  const void* embed= d_in[18];

  char* ws = (char*)d_ws;
  UINT*   counts = (UINT*)  (ws + OFF_COUNTS);
  float*  lsum   = (float*) (ws + OFF_LOSS);
  float*  enorm  = (float*) (ws + OFF_ENORM);
  USHORT* W1p = (USHORT*)(ws + OFF_W1);
  USHORT* W2p = (USHORT*)(ws + OFF_W2);
  USHORT* W3p = (USHORT*)(ws + OFF_W3);
  USHORT* Wmup= (USHORT*)(ws + OFF_WMU);
  USHORT* Wep = (USHORT*)(ws + OFF_WE);
  USHORT* W4p = (USHORT*)(ws + OFF_W4);
  USHORT* W5p = (USHORT*)(ws + OFF_W5);
  USHORT* W6p = (USHORT*)(ws + OFF_W6);
  USHORT* Wop = (USHORT*)(ws + OFF_WO);

  dim3 pgrid(544, 11, 1);
  vq_prep_kernel<<<pgrid, 256, 0, stream>>>(
      x, fc1w, fc2w, fc3w, muw, fc4w, fc5w, fc6w, outw, embed,
      W1p, W2p, W3p, Wmup, Wep, W4p, W5p, W6p, Wop, enorm, counts, lsum);

  vq_main_kernel<<<2048, 256, 0, stream>>>(
      x, c, fc1b, fc2b, fc3b, mub, fc4b, fc5b, fc6b, outb, embed,
      W1p, W2p, W3p, Wmup, Wep, enorm,
      W4p, W5p, W6p, Wop, counts, lsum, d_out);

  vq_fin_kernel<<<1, 256, 0, stream>>>(x, counts, lsum, d_out);
}

// Round 2
// 1180.223 us; speedup vs baseline: 1.5228x; 1.1313x over previous
//
#include <hip/hip_runtime.h>

// ---------------------------------------------------------------------------
// PoseVQVAE fused forward. DUAL-MODE storage dtype (f32 vs bf16) sniffed
// on-device. Math core: bf16 MFMA (32x32x16 main path), encoder 3-plane
// splits (truncation split on READ from f32 LDS acts), decoder 1-plane.
// This round: 32-row waves + 4-way column split -> B-panels read once per
// block (halves L2 traffic), 2x FLOP/mfma-instr, cheaper trunc-split.
// ---------------------------------------------------------------------------

using short8 = __attribute__((ext_vector_type(8))) short;
using f32x4  = __attribute__((ext_vector_type(4))) float;
using f32x16 = __attribute__((ext_vector_type(16))) float;

#define USHORT unsigned short
#define UINT   unsigned int

// plane sizes in ushorts
#define PS_W1  139264   // 544*256
#define PS_W2  65536    // 256*256
#define PS_MU  16384    // 256*64
#define PS_WE  65536    // 64*1024

// LDS geometry
#define STRF 260        // f32 activation stride
#define STRA 360        // dec sA stride (ushort)
#define STRB 264        // dec sB stride (ushort)

// ---- ws layout (bytes), 64B-aligned ----
static const size_t OFF_COUNTS = 262144;    // 1024*4
static const size_t OFF_LOSS   = 266240;    // 4 (+pad)
static const size_t OFF_ENORM  = 266304;    // 1024*4
static const size_t OFF_W1     = 270400;    // 3 planes * 139264 * 2 = 835584
static const size_t OFF_W2     = 1105984;   // 3*65536*2 = 393216
static const size_t OFF_W3     = 1499200;   // 393216
static const size_t OFF_WMU    = 1892416;   // 3*16384*2 = 98304
static const size_t OFF_WE     = 1990720;   // 3*65536*2 = 393216
static const size_t OFF_W4     = 2383936;   // 352*256*2 = 180224
static const size_t OFF_W5     = 2564160;   // 131072
static const size_t OFF_W6     = 2695232;   // 131072
static const size_t OFF_WO     = 2826304;   // 256*288*2 = 147456 -> end ~2.98MB

__device__ __forceinline__ float b2f(USHORT u){
  return __uint_as_float(((UINT)u) << 16);
}
__device__ __forceinline__ USHORT f2b(float f){            // RNE f32->bf16
  UINT u = __float_as_uint(f);
  u += 0x7fffu + ((u >> 16) & 1u);
  return (USHORT)(u >> 16);
}
__device__ __forceinline__ float loadF(const void* p, long i, int f32m){
  if (f32m) return ((const float*)p)[i];
  return b2f(((const USHORT*)p)[i]);
}
// RNE 3-plane split (prep / weights; validated numerics)
__device__ __forceinline__ void split3(float h, USHORT& a, USHORT& b, USHORT& c){
  a = f2b(h); float r = h - b2f(a);
  b = f2b(r); r -= b2f(b);
  c = f2b(r);
}
// truncation 3-plane split (hot path): a+b+c == h to ~2^-24, 7-9 VALU ops
__device__ __forceinline__ void splitT(float h, USHORT& a, USHORT& b, USHORT& c){
  UINT u = __float_as_uint(h);
  a = (USHORT)(u >> 16);
  float r = h - __uint_as_float(u & 0xffff0000u);
  UINT v = __float_as_uint(r);
  b = (USHORT)(v >> 16);
  float r2 = r - __uint_as_float(v & 0xffff0000u);
  c = f2b(r2);
}
__device__ __forceinline__ f32x4 mfma16(short8 a, short8 b, f32x4 c){
  return __builtin_amdgcn_mfma_f32_16x16x32_bf16(a, b, c, 0, 0, 0);
}
__device__ __forceinline__ f32x16 mfma32(short8 a, short8 b, f32x16 c){
  return __builtin_amdgcn_mfma_f32_32x32x16_bf16(a, b, c, 0, 0, 0);
}
__device__ __forceinline__ void zero16(f32x16& v){
  #pragma unroll
  for (int i = 0; i < 16; ++i) v[i] = 0.f;
}
// build 3 A-planes from 8 consecutive f32 in LDS (trunc split)
__device__ __forceinline__ void splitAT(const float* p, short8& A0, short8& A1, short8& A2){
  #pragma unroll
  for (int j = 0; j < 8; ++j){
    USHORT t0, t1, t2; splitT(p[j], t0, t1, t2);
    A0[j] = (short)t0; A1[j] = (short)t1; A2[j] = (short)t2;
  }
}
// dtype sniff (wave-uniform): bf16 storage -> low u16 exponent in [117,130]
__device__ __forceinline__ int detect_f32(const void* x){
  UINT u = ((const UINT*)x)[threadIdx.x & 63];
  int e = (int)((u >> 7) & 0xFFu);
  unsigned long long m = __ballot(e >= 117 && e <= 130);
  return __popcll(m) < 32;
}

// ---------------------------------------------------------------------------
// prep: repack weights into [K/8][N][8] bf16 planes; enorm; zero accums.
// ---------------------------------------------------------------------------
__device__ __forceinline__ void fillW(USHORT* dst, const void* src,
                                      int Kpad, int N, int Ksrc, int Nsrc,
                                      int srcStride, bool kmajor, int t,
                                      int f32m, int planes)
{
  int total = Kpad * N;
  if (t >= total) return;
  int j = t & 7, rest = t >> 3;
  int n = rest % N, kg = rest / N;
  int k = kg*8 + j;
  float v = 0.f;
  if (k < Ksrc && n < Nsrc)
    v = loadF(src, kmajor ? (long)k*srcStride + n : (long)n*srcStride + k, f32m);
  if (planes == 1){ dst[t] = f2b(v); return; }
  USHORT t0, t1, t2; split3(v, t0, t1, t2);
  dst[t] = t0; dst[total + t] = t1; dst[2*total + t] = t2;
}

__global__ void vq_prep_kernel(
    const void* xx,
    const void* fc1w, const void* fc2w, const void* fc3w,
    const void* muw,  const void* fc4w, const void* fc5w,
    const void* fc6w, const void* outw, const void* embed,
    USHORT* W1p, USHORT* W2p, USHORT* W3p, USHORT* Wmup, USHORT* Wep,
    USHORT* W4p, USHORT* W5p, USHORT* W6p, USHORT* Wop,
    float* enorm, UINT* counts, float* loss_sum)
{
  int f32m = detect_f32(xx);
  int t = blockIdx.x * 256 + threadIdx.x;
  switch (blockIdx.y){
    case 0: fillW(W1p,  fc1w, 544, 256, 534, 256, 534, false, t, f32m, 3); break;
    case 1: fillW(W2p,  fc2w, 256, 256, 256, 256, 256, false, t, f32m, 3); break;
    case 2: fillW(W3p,  fc3w, 256, 256, 256, 256, 256, false, t, f32m, 3); break;
    case 3: fillW(Wmup, muw,  256,  64, 256,  64, 256, false, t, f32m, 3); break;
    case 4: fillW(Wep,  embed, 64, 1024, 64, 1024, 1024, true, t, f32m, 3); break;
    case 5: fillW(W4p,  fc4w, 352, 256, 331, 256, 331, false, t, f32m, 1); break;
    case 6: fillW(W5p,  fc5w, 256, 256, 256, 256, 256, false, t, f32m, 1); break;
    case 7: fillW(W6p,  fc6w, 256, 256, 256, 256, 256, false, t, f32m, 1); break;
    case 8: fillW(Wop,  outw, 256, 288, 256, 267, 256, false, t, f32m, 1); break;
    case 9:
      if (t < 1024){
        double s = 0.0;
        for (int l = 0; l < 64; ++l){
          double e = (double)loadF(embed, (long)l*1024 + t, f32m); s += e*e;
        }
        enorm[t] = (float)s;
      }
      break;
    case 10:
      if (t < 1024) counts[t] = 0u;
      if (t == 1024) *loss_sum = 0.f;
      break;
  }
}

// ---------------------------------------------------------------------------
// fused main: 32 rows/block, 256 threads (4 waves).
// Wave w owns ALL 32 rows x 64-col slice (tb0 = w*64) -> B read once/block.
// MFMA 32x32x16: A row = lane&31, k = (lane>>5)*8 + j;
//                C/D: col = lane&31, row = (reg&3) + 8*(reg>>2) + 4*(lane>>5)
// ---------------------------------------------------------------------------
__global__ __launch_bounds__(256, 4) void vq_main_kernel(
    const void* __restrict__ x,  const void* __restrict__ cc,
    const void* __restrict__ b1, const void* __restrict__ b2,
    const void* __restrict__ b3, const void* __restrict__ bmu,
    const void* __restrict__ b4, const void* __restrict__ b5,
    const void* __restrict__ b6, const void* __restrict__ bo,
    const void* __restrict__ embed,
    const USHORT* __restrict__ W1p, const USHORT* __restrict__ W2p,
    const USHORT* __restrict__ W3p, const USHORT* __restrict__ Wmup,
    const USHORT* __restrict__ Wep, const float* __restrict__ enorm,
    const USHORT* __restrict__ W4p, const USHORT* __restrict__ W5p,
    const USHORT* __restrict__ W6p, const USHORT* __restrict__ Wop,
    UINT* __restrict__ counts, float* __restrict__ loss_sum,
    void* __restrict__ out)
{
  // union buffer: enc f32 acts [32][260] (33280B) ALIASED with
  // dec sA [32][360] bf16 (23040B) + sB [32][264] bf16 (16896B) = 39936B
  __shared__ __align__(16) char U[39936];
  __shared__ float rMin[4][32];
  __shared__ int   rCode[4][32];        // rCode[0] becomes the codes[] after combine
  float*  sF = (float*)U;
  USHORT* sA = (USHORT*)U;
  USHORT* sB = (USHORT*)(U + 23040);

  const int f32m = detect_f32(x);
  const int tid  = threadIdx.x;
  const int w    = tid >> 6;
  const int lane = tid & 63;
  const int hi   = lane >> 5;
  const int nn   = lane & 31;
  const int quad = lane >> 4;
  const int l16  = lane & 15;
  const int tb0  = w * 64;                   // this wave's 64-col slice
  const long gbase = (long)blockIdx.x * 32;
  const long gr    = gbase + nn;             // global row for A fragments

  f32x16 acc0, acc1;
  zero16(acc0); zero16(acc1);

  // ================= encoder =================
  // ---- fc1: K=544 (34 k-steps of 16); A from global, trunc 3-plane split
  for (int ks = 0; ks < 34; ++ks){
    short8 A0, A1, A2;
    if (f32m){
      #pragma unroll
      for (int j = 0; j < 8; ++j){
        int col = ks*16 + hi*8 + j;
        float v = 0.f;
        if (col < 267)      v = ((const float*)x)[gr*267 + col];
        else if (col < 534) v = ((const float*)cc)[gr*267 + (col - 267)];
        USHORT t0, t1, t2; splitT(v, t0, t1, t2);
        A0[j] = (short)t0; A1[j] = (short)t1; A2[j] = (short)t2;
      }
    } else {
      #pragma unroll
      for (int j = 0; j < 8; ++j){
        int col = ks*16 + hi*8 + j;
        USHORT u = 0;
        if (col < 267)      u = ((const USHORT*)x)[gr*267 + col];
        else if (col < 534) u = ((const USHORT*)cc)[gr*267 + (col - 267)];
        A0[j] = (short)u;
      }
    }
    const USHORT* bp = W1p + (((ks*2 + hi)*256) + tb0 + nn)*8;
    short8 B00 = *(const short8*)bp;
    short8 B01 = *(const short8*)(bp + 256);
    if (!f32m){
      acc0 = mfma32(A0, B00, acc0); acc1 = mfma32(A0, B01, acc1);
    } else {
      short8 B10 = *(const short8*)(bp + PS_W1);
      short8 B11 = *(const short8*)(bp + PS_W1 + 256);
      short8 B20 = *(const short8*)(bp + 2*PS_W1);
      short8 B21 = *(const short8*)(bp + 2*PS_W1 + 256);
      acc0 = mfma32(A0, B00, acc0); acc1 = mfma32(A0, B01, acc1);
      acc0 = mfma32(A1, B00, acc0); acc1 = mfma32(A1, B01, acc1);
      acc0 = mfma32(A2, B00, acc0); acc1 = mfma32(A2, B01, acc1);
      acc0 = mfma32(A0, B10, acc0); acc1 = mfma32(A0, B11, acc1);
      acc0 = mfma32(A1, B10, acc0); acc1 = mfma32(A1, B11, acc1);
      acc0 = mfma32(A0, B20, acc0); acc1 = mfma32(A0, B21, acc1);
    }
  }
  {
    float bs0 = loadF(b1, tb0 + nn, f32m);
    float bs1 = loadF(b1, tb0 + 32 + nn, f32m);
    #pragma unroll
    for (int reg = 0; reg < 16; ++reg){
      int r = (reg&3) + 8*(reg>>2) + 4*hi;
      sF[r*STRF + tb0 + nn]      = fmaxf(acc0[reg] + bs0, 0.f);
      sF[r*STRF + tb0 + 32 + nn] = fmaxf(acc1[reg] + bs1, 0.f);
    }
  }
  __syncthreads();

  // ---- fc2, fc3: in-place f32 LDS, trunc-split-on-read, K=256 (16 k-steps)
  for (int layer = 0; layer < 2; ++layer){
    const USHORT* Wp = layer ? W3p : W2p;
    const void*   bb = layer ? (const void*)b3 : (const void*)b2;
    zero16(acc0); zero16(acc1);
    #pragma unroll 2
    for (int ks = 0; ks < 16; ++ks){
      short8 A0, A1, A2;
      splitAT(&sF[nn*STRF + ks*16 + hi*8], A0, A1, A2);
      const USHORT* bp = Wp + (((ks*2 + hi)*256) + tb0 + nn)*8;
      short8 B00 = *(const short8*)bp;
      short8 B01 = *(const short8*)(bp + 256);
      acc0 = mfma32(A0, B00, acc0); acc1 = mfma32(A0, B01, acc1);
      acc0 = mfma32(A1, B00, acc0); acc1 = mfma32(A1, B01, acc1);
      acc0 = mfma32(A2, B00, acc0); acc1 = mfma32(A2, B01, acc1);
      if (f32m){
        short8 B10 = *(const short8*)(bp + PS_W2);
        short8 B11 = *(const short8*)(bp + PS_W2 + 256);
        short8 B20 = *(const short8*)(bp + 2*PS_W2);
        short8 B21 = *(const short8*)(bp + 2*PS_W2 + 256);
        acc0 = mfma32(A0, B10, acc0); acc1 = mfma32(A0, B11, acc1);
        acc0 = mfma32(A1, B10, acc0); acc1 = mfma32(A1, B11, acc1);
        acc0 = mfma32(A0, B20, acc0); acc1 = mfma32(A0, B21, acc1);
      }
    }
    __syncthreads();
    {
      float bs0 = loadF(bb, tb0 + nn, f32m);
      float bs1 = loadF(bb, tb0 + 32 + nn, f32m);
      #pragma unroll
      for (int reg = 0; reg < 16; ++reg){
        int r = (reg&3) + 8*(reg>>2) + 4*hi;
        sF[r*STRF + tb0 + nn]      = fmaxf(acc0[reg] + bs0, 0.f);
        sF[r*STRF + tb0 + 32 + nn] = fmaxf(acc1[reg] + bs1, 0.f);
      }
    }
    __syncthreads();
  }

  // ---- mu: N=64, 16x16x32 (wave w -> 16-col tile), dual row-groups, no relu
  {
    f32x4 am0, am1;
    #pragma unroll
    for (int i = 0; i < 4; ++i){ am0[i] = 0.f; am1[i] = 0.f; }
    #pragma unroll 2
    for (int kc = 0; kc < 8; ++kc){
      short8 A0a, A1a, A2a, A0b, A1b, A2b;
      splitAT(&sF[l16*STRF + kc*32 + quad*8],        A0a, A1a, A2a);
      splitAT(&sF[(l16 + 16)*STRF + kc*32 + quad*8], A0b, A1b, A2b);
      const USHORT* bp = Wmup + ((kc*4 + quad)*64 + w*16 + l16)*8;
      short8 Bm0 = *(const short8*)bp;
      am0 = mfma16(A0a, Bm0, am0); am1 = mfma16(A0b, Bm0, am1);
      am0 = mfma16(A1a, Bm0, am0); am1 = mfma16(A1b, Bm0, am1);
      am0 = mfma16(A2a, Bm0, am0); am1 = mfma16(A2b, Bm0, am1);
      if (f32m){
        short8 Bm1 = *(const short8*)(bp + PS_MU);
        am0 = mfma16(A0a, Bm1, am0); am1 = mfma16(A0b, Bm1, am1);
        am0 = mfma16(A1a, Bm1, am0); am1 = mfma16(A1b, Bm1, am1);
        short8 Bm2 = *(const short8*)(bp + 2*PS_MU);
        am0 = mfma16(A0a, Bm2, am0); am1 = mfma16(A0b, Bm2, am1);
      }
    }
    __syncthreads();
    float bm = loadF(bmu, w*16 + l16, f32m);
    #pragma unroll
    for (int r = 0; r < 4; ++r){
      sF[(quad*4 + r)*STRF + w*16 + l16]        = am0[r] + bm;
      sF[(quad*4 + r + 16)*STRF + w*16 + l16]   = am1[r] + bm;
    }
    __syncthreads();
  }

  // ---- VQ: argmin_k(||e_k||^2 - 2 mu.e_k); wave w scans codes [w*256, +256)
  {
    short8 MA0[4], MA1[4], MA2[4];
    #pragma unroll
    for (int ks = 0; ks < 4; ++ks)
      splitAT(&sF[nn*STRF + ks*16 + hi*8], MA0[ks], MA1[ks], MA2[ks]);
    float minv[16]; int minc[16];
    #pragma unroll
    for (int i = 0; i < 16; ++i){ minv[i] = 3.4e38f; minc[i] = 0; }
    for (int tt = 0; tt < 8; ++tt){              // 32 codes per tile
      int cb = w*256 + tt*32;
      f32x16 ad; zero16(ad);
      #pragma unroll
      for (int ks = 0; ks < 4; ++ks){
        const USHORT* bp = Wep + (((ks*2 + hi)*1024) + cb + nn)*8;
        short8 B0 = *(const short8*)bp;
        ad = mfma32(MA0[ks], B0, ad);
        ad = mfma32(MA1[ks], B0, ad);
        ad = mfma32(MA2[ks], B0, ad);
        if (f32m){
          short8 B1 = *(const short8*)(bp + PS_WE);
          ad = mfma32(MA0[ks], B1, ad);
          ad = mfma32(MA1[ks], B1, ad);
          short8 B2 = *(const short8*)(bp + 2*PS_WE);
          ad = mfma32(MA0[ks], B2, ad);
        }
      }
      int code = cb + nn;
      float en = enorm[code];
      #pragma unroll
      for (int reg = 0; reg < 16; ++reg){
        float d = en - 2.f*ad[reg];
        if (d < minv[reg] || (d == minv[reg] && code < minc[reg])){ minv[reg] = d; minc[reg] = code; }
      }
    }
    // reduce across the 32 code-lanes of each half (rows differ by half!)
    #pragma unroll
    for (int off = 16; off >= 1; off >>= 1){
      #pragma unroll
      for (int reg = 0; reg < 16; ++reg){
        float ov = __shfl_xor(minv[reg], off, 64);
        int   oc = __shfl_xor(minc[reg], off, 64);
        if (ov < minv[reg] || (ov == minv[reg] && oc < minc[reg])){ minv[reg] = ov; minc[reg] = oc; }
      }
    }
    if (nn == 0){
      #pragma unroll
      for (int reg = 0; reg < 16; ++reg){
        int r = (reg&3) + 8*(reg>>2) + 4*hi;
        rMin[w][r]  = minv[reg];
        rCode[w][r] = minc[reg];
      }
    }
  }
  __syncthreads();

  // combine the 4 wave-quarters (ascending -> lowest-index tie-break), histogram
  if (tid < 32){
    float bv = rMin[0][tid]; int bc = rCode[0][tid];
    #pragma unroll
    for (int ww = 1; ww < 4; ++ww){
      float v = rMin[ww][tid]; int cd = rCode[ww][tid];
      if (v < bv || (v == bv && cd < bc)){ bv = v; bc = cd; }
    }
    rCode[0][tid] = bc;                      // codes[]
    atomicAdd(&counts[bc], 1u);
  }
  __syncthreads();

  // ---- loss: thread t -> (row = t>>3, dims (t&7)*8 ..+8)
  {
    int lrow = tid >> 3;
    int j0 = (tid & 7) * 8;
    int code = rCode[0][lrow];
    float lp = 0.f;
    #pragma unroll
    for (int jj = 0; jj < 8; ++jj){
      int l = j0 + jj;
      float qv = loadF(embed, (long)l*1024 + code, f32m);
      float d = qv - sF[lrow*STRF + l];
      lp += d*d;
    }
    #pragma unroll
    for (int off = 32; off >= 1; off >>= 1) lp += __shfl_xor(lp, off, 64);
    if (lane == 0) rMin[0][w] = lp;
  }
  __syncthreads();                            // sF reads done; sA may be written
  if (tid == 0)
    atomicAdd(loss_sum, rMin[0][0] + rMin[0][1] + rMin[0][2] + rMin[0][3]);

  // ================= decoder (bf16 1-plane) =================
  // stage s2 = [q | c | 0pad], width 360 (331 used)
  {
    // q: from Wep plane0 ( == f2b(embed) ), 8 contiguous short8 per row
    int rr = tid >> 3, jg = tid & 7;
    int code = rCode[0][rr];
    short8 qv = *(const short8*)(Wep + ((long)jg*1024 + code)*8);
    *(short8*)&sA[rr*STRA + jg*8] = qv;
  }
  for (int rr = w*8; rr < w*8 + 8; ++rr){
    long grow = gbase + rr;
    for (int col = 64 + lane; col < 360; col += 64){
      float v = (col < 331) ? loadF(cc, grow*267 + (col - 64), f32m) : 0.f;
      sA[rr*STRA + col] = f2b(v);
    }
  }
  __syncthreads();

  // ---- fc4: K=352 (22 k-steps) : sA -> sB
  zero16(acc0); zero16(acc1);
  #pragma unroll 2
  for (int ks = 0; ks < 22; ++ks){
    short8 A = *(const short8*)&sA[nn*STRA + ks*16 + hi*8];
    const USHORT* bp = W4p + (((ks*2 + hi)*256) + tb0 + nn)*8;
    acc0 = mfma32(A, *(const short8*)bp,         acc0);
    acc1 = mfma32(A, *(const short8*)(bp + 256), acc1);
  }
  {
    float bs0 = loadF(b4, tb0 + nn, f32m);
    float bs1 = loadF(b4, tb0 + 32 + nn, f32m);
    #pragma unroll
    for (int reg = 0; reg < 16; ++reg){
      int r = (reg&3) + 8*(reg>>2) + 4*hi;
      sB[r*STRB + tb0 + nn]      = f2b(fmaxf(acc0[reg] + bs0, 0.f));
      sB[r*STRB + tb0 + 32 + nn] = f2b(fmaxf(acc1[reg] + bs1, 0.f));
    }
  }
  __syncthreads();

  // ---- fc5: sB -> sA (in-place-flip: barrier between read and write)
  zero16(acc0); zero16(acc1);
  #pragma unroll 4
  for (int ks = 0; ks < 16; ++ks){
    short8 A = *(const short8*)&sB[nn*STRB + ks*16 + hi*8];
    const USHORT* bp = W5p + (((ks*2 + hi)*256) + tb0 + nn)*8;
    acc0 = mfma32(A, *(const short8*)bp,         acc0);
    acc1 = mfma32(A, *(const short8*)(bp + 256), acc1);
  }
  __syncthreads();
  {
    float bs0 = loadF(b5, tb0 + nn, f32m);
    float bs1 = loadF(b5, tb0 + 32 + nn, f32m);
    #pragma unroll
    for (int reg = 0; reg < 16; ++reg){
      int r = (reg&3) + 8*(reg>>2) + 4*hi;
      sA[r*STRA + tb0 + nn]      = f2b(fmaxf(acc0[reg] + bs0, 0.f));
      sA[r*STRA + tb0 + 32 + nn] = f2b(fmaxf(acc1[reg] + bs1, 0.f));
    }
  }
  __syncthreads();

  // ---- fc6: sA -> sB
  zero16(acc0); zero16(acc1);
  #pragma unroll 4
  for (int ks = 0; ks < 16; ++ks){
    short8 A = *(const short8*)&sA[nn*STRA + ks*16 + hi*8];
    const USHORT* bp = W6p + (((ks*2 + hi)*256) + tb0 + nn)*8;
    acc0 = mfma32(A, *(const short8*)bp,         acc0);
    acc1 = mfma32(A, *(const short8*)(bp + 256), acc1);
  }
  __syncthreads();
  {
    float bs0 = loadF(b6, tb0 + nn, f32m);
    float bs1 = loadF(b6, tb0 + 32 + nn, f32m);
    #pragma unroll
    for (int reg = 0; reg < 16; ++reg){
      int r = (reg&3) + 8*(reg>>2) + 4*hi;
      sB[r*STRB + tb0 + nn]      = f2b(fmaxf(acc0[reg] + bs0, 0.f));
      sB[r*STRB + tb0 + 32 + nn] = f2b(fmaxf(acc1[reg] + bs1, 0.f));
    }
  }
  __syncthreads();

  // ---- out: N=288 padded (267 real); waves 0-2: 2 tiles, wave 3: 3 tiles
  {
    f32x16 acco0, acco1, acco2;
    zero16(acco0); zero16(acco1); zero16(acco2);
    #pragma unroll 2
    for (int ks = 0; ks < 16; ++ks){
      short8 A = *(const short8*)&sB[nn*STRB + ks*16 + hi*8];
      const USHORT* bp = Wop + (((ks*2 + hi)*288) + w*64 + nn)*8;
      acco0 = mfma32(A, *(const short8*)bp,         acco0);
      acco1 = mfma32(A, *(const short8*)(bp + 256), acco1);
      if (w == 3) acco2 = mfma32(A, *(const short8*)(bp + 512), acco2);
    }
    int ntiles = (w == 3) ? 3 : 2;
    #pragma unroll
    for (int t = 0; t < 3; ++t){
      if (t < ntiles){
        int col = w*64 + t*32 + nn;
        if (col < 267){
          float bias = loadF(bo, col, f32m);
          f32x16& a = (t == 0) ? acco0 : (t == 1) ? acco1 : acco2;
          #pragma unroll
          for (int reg = 0; reg < 16; ++reg){
            int r = (reg&3) + 8*(reg>>2) + 4*hi;
            long oi = (gbase + r)*267 + col;
            float val = a[reg] + bias;
            if (f32m) ((float*)out)[oi] = val;
            else      ((USHORT*)out)[oi] = f2b(val);
          }
        }
      }
    }
  }
}

// ---------------------------------------------------------------------------
// finalize: loss mean + perplexity from histogram
// ---------------------------------------------------------------------------
__global__ void vq_fin_kernel(const void* __restrict__ x,
                              const UINT* __restrict__ counts,
                              const float* __restrict__ loss_sum,
                              void* __restrict__ out)
{
  __shared__ float red[4];
  int f32m = detect_f32(x);
  int tid = threadIdx.x;
  float Hl = 0.f;
  for (int k = tid; k < 1024; k += 256){
    float p = (float)counts[k] * (1.f/65536.f);
    Hl -= p * logf(p + 1e-10f);
  }
  #pragma unroll
  for (int off = 32; off >= 1; off >>= 1) Hl += __shfl_xor(Hl, off, 64);
  if ((tid & 63) == 0) red[tid >> 6] = Hl;
  __syncthreads();
  if (tid == 0){
    float H = red[0] + red[1] + red[2] + red[3];
    float loss = *loss_sum * (1.f/4194304.f);   // /(B*L)
    float ppx  = expf(H);
    size_t base = (size_t)65536*267;
    if (f32m){
      ((float*)out)[base]     = loss;
      ((float*)out)[base + 1] = ppx;
    } else {
      ((USHORT*)out)[base]     = f2b(loss);
      ((USHORT*)out)[base + 1] = f2b(ppx);
    }
  }
}

// ---------------------------------------------------------------------------
extern "C" void kernel_launch(void* const* d_in, const int* in_sizes, int n_in,
                              void* d_out, int out_size, void* d_ws, size_t ws_size,
                              hipStream_t stream)
{
  const void* x    = d_in[0];
  const void* c    = d_in[1];
  const void* fc1w = d_in[2];
  const void* fc1b = d_in[3];
  const void* fc2w = d_in[4];
  const void* fc2b = d_in[5];
  const void* fc3w = d_in[6];
  const void* fc3b = d_in[7];
  const void* muw  = d_in[8];
  const void* mub  = d_in[9];
  const void* fc4w = d_in[10];
  const void* fc4b = d_in[11];
  const void* fc5w = d_in[12];
  const void* fc5b = d_in[13];
  const void* fc6w = d_in[14];
  const void* fc6b = d_in[15];
  const void* outw = d_in[16];
  const void* outb = d_in[17];
  const void* embed= d_in[18];

  char* ws = (char*)d_ws;
  UINT*   counts = (UINT*)  (ws + OFF_COUNTS);
  float*  lsum   = (float*) (ws + OFF_LOSS);
  float*  enorm  = (float*) (ws + OFF_ENORM);
  USHORT* W1p = (USHORT*)(ws + OFF_W1);
  USHORT* W2p = (USHORT*)(ws + OFF_W2);
  USHORT* W3p = (USHORT*)(ws + OFF_W3);
  USHORT* Wmup= (USHORT*)(ws + OFF_WMU);
  USHORT* Wep = (USHORT*)(ws + OFF_WE);
  USHORT* W4p = (USHORT*)(ws + OFF_W4);
  USHORT* W5p = (USHORT*)(ws + OFF_W5);
  USHORT* W6p = (USHORT*)(ws + OFF_W6);
  USHORT* Wop = (USHORT*)(ws + OFF_WO);

  dim3 pgrid(544, 11, 1);
  vq_prep_kernel<<<pgrid, 256, 0, stream>>>(
      x, fc1w, fc2w, fc3w, muw, fc4w, fc5w, fc6w, outw, embed,
      W1p, W2p, W3p, Wmup, Wep, W4p, W5p, W6p, Wop, enorm, counts, lsum);

  vq_main_kernel<<<2048, 256, 0, stream>>>(
      x, c, fc1b, fc2b, fc3b, mub, fc4b, fc5b, fc6b, outb, embed,
      W1p, W2p, W3p, Wmup, Wep, enorm,
      W4p, W5p, W6p, Wop, counts, lsum, d_out);

  vq_fin_kernel<<<1, 256, 0, stream>>>(x, counts, lsum, d_out);
}